// Round 4
// baseline (278.560 us; speedup 1.0000x reference)
//
#include <hip/hip_runtime.h>

#define NTAG 32
#define START 30
#define STOP 31
#define LOG2E 1.44269504088896340736f
#define LN2 0.69314718055994530942f

__device__ __forceinline__ float fexp2(float x) {
#if __has_builtin(__builtin_amdgcn_exp2f)
    return __builtin_amdgcn_exp2f(x);   // v_exp_f32: 2^x
#else
    return exp2f(x);
#endif
}
__device__ __forceinline__ float flog2(float x) {
#if __has_builtin(__builtin_amdgcn_logf)
    return __builtin_amdgcn_logf(x);    // v_log_f32: log2(x)
#else
    return log2f(x);
#endif
}

#define REPEAT32(M) \
    M(0) M(1) M(2) M(3) M(4) M(5) M(6) M(7) \
    M(8) M(9) M(10) M(11) M(12) M(13) M(14) M(15) \
    M(16) M(17) M(18) M(19) M(20) M(21) M(22) M(23) \
    M(24) M(25) M(26) M(27) M(28) M(29) M(30) M(31)

// One wave per batch element; lanes 0..31 active, lane j owns tag j.
// Block = 256 threads = 4 waves = 4 batches. Grid = B/4.
__global__ __launch_bounds__(256, 1) void crf_nll_kernel(
    const float* __restrict__ feats,   // B x L x 32
    const float* __restrict__ trans,   // 32 x 32
    const int*   __restrict__ tags,    // B x L
    const int*   __restrict__ wsl,     // B
    float* __restrict__ out, int B, int L)
{
    __shared__ float strans[NTAG * NTAG];
    for (int i = threadIdx.x; i < NTAG * NTAG; i += 256) strans[i] = trans[i];
    __syncthreads();

    const int wave = threadIdx.x >> 6;
    const int lane = threadIdx.x & 63;
    int b = blockIdx.x * 4 + wave;
    b = __builtin_amdgcn_readfirstlane(b);
    if (lane >= 32 || b >= B) return;
    const int j = lane;

    // per-lane column of exp2(trans*log2e), as 32 NAMED scalars -> guaranteed VGPRs
#define DECL_ET2(i) const float ET2_##i = fexp2(strans[(i) * NTAG + j] * LOG2E);
    REPEAT32(DECL_ET2)
#undef DECL_ET2
    const float tS2 = strans[j * NTAG + STOP] * LOG2E;

    const int n = wsl[b];
    const float* __restrict__ frow = feats + (size_t)b * L * NTAG;
    const int*   __restrict__ trow = tags  + (size_t)b * L;

    // ---- init (t = 0) ----
    const float feat0 = frow[j];
    const int tag0 = trow[0];
    // invariant: alpha2_j (log2-domain alpha) == u2h_j - l2mx + M2
    float u2h = (strans[START * NTAG + j] + feat0) * LOG2E;
    float l2mx = 0.f, M2 = 0.f;
    float gacc = (j == tag0) ? (strans[START * NTAG + j] + feat0) : 0.f;
    int tagprev = tag0;

    // ---- prefetch ring: 8 named slots (slot0 = oldest = time t) ----
#define LDF(t_) frow[(((t_) < L - 1) ? (t_) : (L - 1)) * NTAG + j]
#define LDT(t_) trow[(((t_) < L - 1) ? (t_) : (L - 1))]
    float f0 = LDF(1), f1 = LDF(2), f2 = LDF(3), f3 = LDF(4),
          f4 = LDF(5), f5 = LDF(6), f6 = LDF(7), f7 = LDF(8);
    int   g0 = LDT(1), g1 = LDT(2), g2 = LDT(3), g3 = LDT(4),
          g4 = LDT(5), g5 = LDT(6), g6 = LDT(7), g7 = LDT(8);

    // ---- serial scan: t = 1 .. n-1 (single-step body; arrays are all scalars) ----
    for (int t = 1; t < n; ++t) {
        const float fraw = f0;
        const int   tg   = g0;
        // rotate ring, prefetch t+8
        f0 = f1; f1 = f2; f2 = f3; f3 = f4; f4 = f5; f5 = f6; f6 = f7;
        g0 = g1; g1 = g2; g2 = g3; g3 = g4; g4 = g5; g5 = g6; g6 = g7;
        {
            const int tn_ = t + 8;
            f7 = LDF(tn_);
            g7 = LDT(tn_);
        }

        // e_i = 2^(u_i - l2mx_prev)   (lag-1 renorm keeps args bounded)
        const float e = fexp2(u2h - l2mx);
        const int eint = __float_as_int(e);

        float acc[4] = {0.f, 0.f, 0.f, 0.f};
        unsigned mxu = 0u;
#define DOT_TERM(i) { \
        const int eu = __builtin_amdgcn_readlane(eint, (i)); \
        const unsigned uu = (unsigned)eu; \
        mxu = (uu > mxu) ? uu : mxu; \
        acc[(i) & 3] = fmaf(__int_as_float(eu), ET2_##i, acc[(i) & 3]); }
        REPEAT32(DOT_TERM)
#undef DOT_TERM
        const float S = (acc[0] + acc[1]) + (acc[2] + acc[3]);

        // gold: middle term trans[tag_{t-1}, tag_t] + feats[b,t,tag_t] (off chain)
        const float trc = strans[tagprev * NTAG + j];
        gacc += (j == tg) ? (trc + fraw) : 0.f;
        tagprev = tg;

        const float l2S = flog2(S);
        u2h = fmaf(fraw, LOG2E, l2S);
        const float lm = flog2(__uint_as_float(mxu));  // off chain (used next iter)
        M2 += lm;
        l2mx = lm;
    }
#undef LDF
#undef LDT

    // gold: end term = trans[tag_last, STOP]
    {
        const float trl = strans[tagprev * NTAG + j];
        gacc += (j == STOP) ? trl : 0.f;
    }

    // forward score: ln2 * (M2 + log2 sum_j 2^(u2_j + tS2_j))
    float v  = u2h - l2mx + tS2;
    float ex = fexp2(v);
#pragma unroll
    for (int k = 1; k < 32; k <<= 1) {
        ex   += __shfl_xor(ex,   k, 32);
        gacc += __shfl_xor(gacc, k, 32);
    }
    if (j == 0) {
        const float fs = LN2 * (M2 + flog2(ex));
        atomicAdd(out, fs - gacc);
    }
}

extern "C" void kernel_launch(void* const* d_in, const int* in_sizes, int n_in,
                              void* d_out, int out_size, void* d_ws, size_t ws_size,
                              hipStream_t stream) {
    const float* feats = (const float*)d_in[0];
    const float* trans = (const float*)d_in[1];
    const int*   tags  = (const int*)d_in[2];
    const int*   wsl   = (const int*)d_in[3];
    float* out = (float*)d_out;

    const int B = in_sizes[3];              // word_seq_lens: (B,)
    const int L = in_sizes[2] / B;          // tags: (B, L)

    (void)hipMemsetAsync(out, 0, sizeof(float), stream);
    const int grid = (B + 3) / 4;
    crf_nll_kernel<<<grid, 256, 0, stream>>>(feats, trans, tags, wsl, out, B, L);
}

// Round 5
// 273.715 us; speedup vs baseline: 1.0177x; 1.0177x over previous
//
#include <hip/hip_runtime.h>

#define NTAG 32
#define START 30
#define STOP 31
#define LOG2E 1.44269504088896340736f
#define LN2 0.69314718055994530942f

__device__ __forceinline__ float fexp2(float x) {
#if __has_builtin(__builtin_amdgcn_exp2f)
    return __builtin_amdgcn_exp2f(x);   // v_exp_f32: 2^x
#else
    return exp2f(x);
#endif
}
__device__ __forceinline__ float flog2(float x) {
#if __has_builtin(__builtin_amdgcn_logf)
    return __builtin_amdgcn_logf(x);    // v_log_f32: log2(x)
#else
    return log2f(x);
#endif
}

#define REPEAT32(M) \
    M(0) M(1) M(2) M(3) M(4) M(5) M(6) M(7) \
    M(8) M(9) M(10) M(11) M(12) M(13) M(14) M(15) \
    M(16) M(17) M(18) M(19) M(20) M(21) M(22) M(23) \
    M(24) M(25) M(26) M(27) M(28) M(29) M(30) M(31)

// One wave per batch element; lanes 0..31 active, lane j owns tag j.
// Block = 256 threads = 4 waves = 4 batches. Grid = B/4 -> 1 block/CU, 1 wave/SIMD.
__global__ __launch_bounds__(256, 1) void crf_nll_kernel(
    const float* __restrict__ feats,   // B x L x 32
    const float* __restrict__ trans,   // 32 x 32
    const int*   __restrict__ tags,    // B x L
    const int*   __restrict__ wsl,     // B
    float* __restrict__ out, int B, int L)
{
    __shared__ float strans[NTAG * NTAG];
    for (int i = threadIdx.x; i < NTAG * NTAG; i += 256) strans[i] = trans[i];
    __syncthreads();

    const int wave = threadIdx.x >> 6;
    const int lane = threadIdx.x & 63;
    int b = blockIdx.x * 4 + wave;
    b = __builtin_amdgcn_readfirstlane(b);
    if (lane >= 32 || b >= B) return;
    const int j = lane;

    // per-lane column of exp2(trans*log2e): 32 named scalars, pinned in VGPRs
    // inside the loop by empty asm (see PIN below).
#define DECL_ET2(i) float ET2_##i = fexp2(strans[(i) * NTAG + j] * LOG2E);
    REPEAT32(DECL_ET2)
#undef DECL_ET2
    const float tS2 = strans[j * NTAG + STOP] * LOG2E;

    const int n = wsl[b];
    const float* __restrict__ frow = feats + (size_t)b * L * NTAG;
    const int*   __restrict__ trow = tags  + (size_t)b * L;

    // ---- init (t = 0) ----
    const float feat0 = frow[j];
    const int tag0 = trow[0];
    // invariant: alpha2_j (log2-domain alpha) == u2h_j - l2mx + M2
    float u2h = (strans[START * NTAG + j] + feat0) * LOG2E;
    float l2mx = 0.f, M2 = 0.f;
    float gacc = (j == tag0) ? (strans[START * NTAG + j] + feat0) : 0.f;
    int tagprev = tag0;

    // ---- prefetch ring: 8 named slots (slot0 = oldest = time t) ----
#define LDF(t_) frow[(((t_) < L - 1) ? (t_) : (L - 1)) * NTAG + j]
#define LDT(t_) trow[(((t_) < L - 1) ? (t_) : (L - 1))]
    float f0 = LDF(1), f1 = LDF(2), f2 = LDF(3), f3 = LDF(4),
          f4 = LDF(5), f5 = LDF(6), f6 = LDF(7), f7 = LDF(8);
    int   g0 = LDT(1), g1 = LDT(2), g2 = LDT(3), g3 = LDT(4),
          g4 = LDT(5), g5 = LDT(6), g6 = LDT(7), g7 = LDT(8);

    // ---- serial scan: t = 1 .. n-1 ----
    for (int t = 1; t < n; ++t) {
        // PIN: force all ET2_* to be materialized in VGPRs every iteration.
        // Empty asm, zero instructions; kills spill-to-scratch / remat-from-LDS.
        asm volatile("" : "+v"(ET2_0),  "+v"(ET2_1),  "+v"(ET2_2),  "+v"(ET2_3),
                          "+v"(ET2_4),  "+v"(ET2_5),  "+v"(ET2_6),  "+v"(ET2_7));
        asm volatile("" : "+v"(ET2_8),  "+v"(ET2_9),  "+v"(ET2_10), "+v"(ET2_11),
                          "+v"(ET2_12), "+v"(ET2_13), "+v"(ET2_14), "+v"(ET2_15));
        asm volatile("" : "+v"(ET2_16), "+v"(ET2_17), "+v"(ET2_18), "+v"(ET2_19),
                          "+v"(ET2_20), "+v"(ET2_21), "+v"(ET2_22), "+v"(ET2_23));
        asm volatile("" : "+v"(ET2_24), "+v"(ET2_25), "+v"(ET2_26), "+v"(ET2_27),
                          "+v"(ET2_28), "+v"(ET2_29), "+v"(ET2_30), "+v"(ET2_31));

        const float fraw = f0;
        const int   tg   = g0;
        // rotate ring, prefetch t+8
        f0 = f1; f1 = f2; f2 = f3; f3 = f4; f4 = f5; f5 = f6; f6 = f7;
        g0 = g1; g1 = g2; g2 = g3; g3 = g4; g4 = g5; g5 = g6; g6 = g7;
        {
            const int tn_ = t + 8;
            f7 = LDF(tn_);
            g7 = LDT(tn_);
        }

        // e_i = 2^(u_i - l2mx_prev)   (lag-1 renorm keeps args bounded)
        const float e = fexp2(u2h - l2mx);
        const int eint = __float_as_int(e);

        float a0 = 0.f, a1 = 0.f, a2 = 0.f, a3 = 0.f;
        unsigned mxu = 0u;
#define DOT_TERM(i) { \
        const int eu = __builtin_amdgcn_readlane(eint, (i)); \
        const unsigned uu = (unsigned)eu; \
        mxu = (uu > mxu) ? uu : mxu; \
        const float ef = __int_as_float(eu); \
        if      (((i) & 3) == 0) a0 = fmaf(ef, ET2_##i, a0); \
        else if (((i) & 3) == 1) a1 = fmaf(ef, ET2_##i, a1); \
        else if (((i) & 3) == 2) a2 = fmaf(ef, ET2_##i, a2); \
        else                     a3 = fmaf(ef, ET2_##i, a3); }
        REPEAT32(DOT_TERM)
#undef DOT_TERM
        const float S = (a0 + a1) + (a2 + a3);

        // gold: middle term trans[tag_{t-1}, tag_t] + feats[b,t,tag_t] (off chain)
        const float trc = strans[tagprev * NTAG + j];
        gacc += (j == tg) ? (trc + fraw) : 0.f;
        tagprev = tg;

        const float l2S = flog2(S);
        u2h = fmaf(fraw, LOG2E, l2S);
        const float lm = flog2(__uint_as_float(mxu));  // off chain (used next iter)
        M2 += lm;
        l2mx = lm;
    }
#undef LDF
#undef LDT

    // gold: end term = trans[tag_last, STOP]
    {
        const float trl = strans[tagprev * NTAG + j];
        gacc += (j == STOP) ? trl : 0.f;
    }

    // forward score: ln2 * (M2 + log2 sum_j 2^(u2_j + tS2_j))
    float v  = u2h - l2mx + tS2;
    float ex = fexp2(v);
#pragma unroll
    for (int k = 1; k < 32; k <<= 1) {
        ex   += __shfl_xor(ex,   k, 32);
        gacc += __shfl_xor(gacc, k, 32);
    }
    if (j == 0) {
        const float fs = LN2 * (M2 + flog2(ex));
        atomicAdd(out, fs - gacc);
    }
}

extern "C" void kernel_launch(void* const* d_in, const int* in_sizes, int n_in,
                              void* d_out, int out_size, void* d_ws, size_t ws_size,
                              hipStream_t stream) {
    const float* feats = (const float*)d_in[0];
    const float* trans = (const float*)d_in[1];
    const int*   tags  = (const int*)d_in[2];
    const int*   wsl   = (const int*)d_in[3];
    float* out = (float*)d_out;

    const int B = in_sizes[3];              // word_seq_lens: (B,)
    const int L = in_sizes[2] / B;          // tags: (B, L)

    (void)hipMemsetAsync(out, 0, sizeof(float), stream);
    const int grid = (B + 3) / 4;
    crf_nll_kernel<<<grid, 256, 0, stream>>>(feats, trans, tags, wsl, out, B, L);
}

// Round 6
// 209.016 us; speedup vs baseline: 1.3327x; 1.3095x over previous
//
#include <hip/hip_runtime.h>

#define NTAG 32
#define START 30
#define STOP 31
#define LOG2E 1.44269504088896340736f
#define LN2 0.69314718055994530942f

__device__ __forceinline__ float fexp2(float x) {
#if __has_builtin(__builtin_amdgcn_exp2f)
    return __builtin_amdgcn_exp2f(x);   // v_exp_f32: 2^x
#else
    return exp2f(x);
#endif
}
__device__ __forceinline__ float flog2(float x) {
#if __has_builtin(__builtin_amdgcn_logf)
    return __builtin_amdgcn_logf(x);    // v_log_f32: log2(x)
#else
    return log2f(x);
#endif
}

#define REPEAT32(M) \
    M(0) M(1) M(2) M(3) M(4) M(5) M(6) M(7) \
    M(8) M(9) M(10) M(11) M(12) M(13) M(14) M(15) \
    M(16) M(17) M(18) M(19) M(20) M(21) M(22) M(23) \
    M(24) M(25) M(26) M(27) M(28) M(29) M(30) M(31)

// batched readlanes (all before any FMA -> hazard distance 32)
#define RL_DECL(i) const int eu_##i = __builtin_amdgcn_readlane(eint_, (i));
// scalar-pipe running max (positive floats order as uints)
#define MAX_T(i)  mxu_ = ((unsigned)eu_##i > mxu_) ? (unsigned)eu_##i : mxu_;
// 4-way accumulator FMA block
#define FMA_T(i) { const float ef_ = __int_as_float(eu_##i); \
    if      (((i) & 3) == 0) a0_ = fmaf(ef_, ET2_##i, a0_); \
    else if (((i) & 3) == 1) a1_ = fmaf(ef_, ET2_##i, a1_); \
    else if (((i) & 3) == 2) a2_ = fmaf(ef_, ET2_##i, a2_); \
    else                     a3_ = fmaf(ef_, ET2_##i, a3_); }

// One scan step. FS is a named ring slot (compile-time), tcur is the time index.
// No LDS, no tag loads, exactly one global load (feat prefetch t+8).
#define SCAN_STEP(FS, tcur) { \
    const float fraw_ = FS; \
    { const int tn_ = (tcur) + 8; const int tc_ = (tn_ < L - 1) ? tn_ : (L - 1); \
      FS = frow[tc_ * NTAG + j]; } \
    const float e_ = fexp2(u2h - l2mx); \
    const int eint_ = __float_as_int(e_); \
    REPEAT32(RL_DECL) \
    unsigned mxu_ = 0u; \
    REPEAT32(MAX_T) \
    float a0_ = 0.f, a1_ = 0.f, a2_ = 0.f, a3_ = 0.f; \
    REPEAT32(FMA_T) \
    const float S_ = (a0_ + a1_) + (a2_ + a3_); \
    const float l2S_ = flog2(S_); \
    u2h = fmaf(fraw_, LOG2E, l2S_); \
    const float lm_ = flog2(__uint_as_float(mxu_)); \
    M2 += lm_; l2mx = lm_; }

// Block = 512 threads = 8 waves. Waves 0-3: serial alpha scan, one batch each
// (lanes 0-31 = tags). Waves 4-7: gold-score gathers for the same 4 batches --
// independent waves co-resident on the same SIMDs, filling the scan waves'
// stall cycles. Grid = B/4 = 256 blocks = 1 block/CU.
__global__ __launch_bounds__(512, 2) void crf_nll_kernel(
    const float* __restrict__ feats,   // B x L x 32
    const float* __restrict__ trans,   // 32 x 32
    const int*   __restrict__ tags,    // B x L
    const int*   __restrict__ wsl,     // B
    float* __restrict__ out, int B, int L)
{
    __shared__ float strans[NTAG * NTAG];
    for (int i = threadIdx.x; i < NTAG * NTAG; i += 512) strans[i] = trans[i];
    __syncthreads();

    const int wave = threadIdx.x >> 6;
    const int lane = threadIdx.x & 63;

    if (wave < 4) {
        // ================= scan waves =================
        int b = blockIdx.x * 4 + wave;
        b = __builtin_amdgcn_readfirstlane(b);
        if (lane >= 32 || b >= B) return;
        const int j = lane;

#define DECL_ET2(i) float ET2_##i = fexp2(strans[(i) * NTAG + j] * LOG2E);
        REPEAT32(DECL_ET2)
#undef DECL_ET2
        const float tS2 = strans[j * NTAG + STOP] * LOG2E;

        const int n = wsl[b];
        const float* __restrict__ frow = feats + (size_t)b * L * NTAG;

        // init (t = 0); invariant: log2-alpha_j == u2h_j - l2mx + M2
        float u2h = (strans[START * NTAG + j] + frow[j]) * LOG2E;
        float l2mx = 0.f, M2 = 0.f;

        // prefetch ring: 8 named slots (f0 = oldest)
#define LDF(t_) frow[(((t_) < L - 1) ? (t_) : (L - 1)) * NTAG + j]
        float f0 = LDF(1), f1 = LDF(2), f2 = LDF(3), f3 = LDF(4),
              f4 = LDF(5), f5 = LDF(6), f6 = LDF(7), f7 = LDF(8);
#undef LDF

        int t = 1;
        for (; t + 8 <= n; t += 8) {
            // pin ET2 in VGPRs (zero-instruction insurance against remat/spill)
            asm volatile("" : "+v"(ET2_0),  "+v"(ET2_1),  "+v"(ET2_2),  "+v"(ET2_3),
                              "+v"(ET2_4),  "+v"(ET2_5),  "+v"(ET2_6),  "+v"(ET2_7));
            asm volatile("" : "+v"(ET2_8),  "+v"(ET2_9),  "+v"(ET2_10), "+v"(ET2_11),
                              "+v"(ET2_12), "+v"(ET2_13), "+v"(ET2_14), "+v"(ET2_15));
            asm volatile("" : "+v"(ET2_16), "+v"(ET2_17), "+v"(ET2_18), "+v"(ET2_19),
                              "+v"(ET2_20), "+v"(ET2_21), "+v"(ET2_22), "+v"(ET2_23));
            asm volatile("" : "+v"(ET2_24), "+v"(ET2_25), "+v"(ET2_26), "+v"(ET2_27),
                              "+v"(ET2_28), "+v"(ET2_29), "+v"(ET2_30), "+v"(ET2_31));
            SCAN_STEP(f0, t + 0)
            SCAN_STEP(f1, t + 1)
            SCAN_STEP(f2, t + 2)
            SCAN_STEP(f3, t + 3)
            SCAN_STEP(f4, t + 4)
            SCAN_STEP(f5, t + 5)
            SCAN_STEP(f6, t + 6)
            SCAN_STEP(f7, t + 7)
        }
        // epilogue: up to 7 remaining steps, compile-time ring slots
        if (t + 0 < n) { SCAN_STEP(f0, t + 0) }
        if (t + 1 < n) { SCAN_STEP(f1, t + 1) }
        if (t + 2 < n) { SCAN_STEP(f2, t + 2) }
        if (t + 3 < n) { SCAN_STEP(f3, t + 3) }
        if (t + 4 < n) { SCAN_STEP(f4, t + 4) }
        if (t + 5 < n) { SCAN_STEP(f5, t + 5) }
        if (t + 6 < n) { SCAN_STEP(f6, t + 6) }

        // forward score: ln2 * (M2 + log2 sum_j 2^(u2h_j - l2mx + tS2_j))
        float ex = fexp2(u2h - l2mx + tS2);
#pragma unroll
        for (int k = 1; k < 32; k <<= 1) ex += __shfl_xor(ex, k, 32);
        if (j == 0) atomicAdd(out, LN2 * (M2 + flog2(ex)));
    } else {
        // ================= gold waves (pure gathers, fill scan stalls) =======
        int b = blockIdx.x * 4 + (wave - 4);
        b = __builtin_amdgcn_readfirstlane(b);
        if (b >= B) return;
        const int n = wsl[b];
        const float* __restrict__ frow = feats + (size_t)b * L * NTAG;
        const int*   __restrict__ trow = tags  + (size_t)b * L;

        float acc = 0.f;
        for (int t = lane; t < L; t += 64) {
            const int tg = trow[t];
            if (t == 0) {
                // begin: trans[START, tag0] + feats[b,0,tag0]
                acc += strans[START * NTAG + tg] + frow[tg];
            } else if (t < n) {
                // middle: trans[tag_{t-1}, tag_t] + feats[b,t,tag_t]
                const int tgp = trow[t - 1];
                acc += strans[tgp * NTAG + tg] + frow[t * NTAG + tg];
            }
            if (t == n - 1) {
                // end: trans[tag_{n-1}, STOP]
                acc += strans[tg * NTAG + STOP];
            }
        }
#pragma unroll
        for (int k = 1; k < 64; k <<= 1) acc += __shfl_xor(acc, k, 64);
        if (lane == 0) atomicAdd(out, -acc);
    }
}

extern "C" void kernel_launch(void* const* d_in, const int* in_sizes, int n_in,
                              void* d_out, int out_size, void* d_ws, size_t ws_size,
                              hipStream_t stream) {
    const float* feats = (const float*)d_in[0];
    const float* trans = (const float*)d_in[1];
    const int*   tags  = (const int*)d_in[2];
    const int*   wsl   = (const int*)d_in[3];
    float* out = (float*)d_out;

    const int B = in_sizes[3];              // word_seq_lens: (B,)
    const int L = in_sizes[2] / B;          // tags: (B, L)

    (void)hipMemsetAsync(out, 0, sizeof(float), stream);
    const int grid = (B + 3) / 4;
    crf_nll_kernel<<<grid, 512, 0, stream>>>(feats, trans, tags, wsl, out, B, L);
}

// Round 7
// 175.707 us; speedup vs baseline: 1.5854x; 1.1896x over previous
//
#include <hip/hip_runtime.h>

#define NTAG 32
#define START 30
#define STOP 31
#define LOG2E 1.44269504088896340736f
#define LN2 0.69314718055994530942f

__device__ __forceinline__ float fexp2(float x) {
#if __has_builtin(__builtin_amdgcn_exp2f)
    return __builtin_amdgcn_exp2f(x);   // v_exp_f32: 2^x
#else
    return exp2f(x);
#endif
}
__device__ __forceinline__ float flog2(float x) {
#if __has_builtin(__builtin_amdgcn_logf)
    return __builtin_amdgcn_logf(x);    // v_log_f32: log2(x)
#else
    return log2f(x);
#endif
}
__device__ __forceinline__ float rfl(float x) {
    return __int_as_float(__builtin_amdgcn_readfirstlane(__float_as_int(x)));
}

#define REPEAT32(M) \
    M(0) M(1) M(2) M(3) M(4) M(5) M(6) M(7) \
    M(8) M(9) M(10) M(11) M(12) M(13) M(14) M(15) \
    M(16) M(17) M(18) M(19) M(20) M(21) M(22) M(23) \
    M(24) M(25) M(26) M(27) M(28) M(29) M(30) M(31)

// batched readlanes (all before any FMA -> hazard distance 32)
#define RL_DECL(i) const int eu_##i = __builtin_amdgcn_readlane(eint_, (i));
// 4-way accumulator FMA block
#define FMA_T(i) { const float ef_ = __int_as_float(eu_##i); \
    if      (((i) & 3) == 0) a0_ = fmaf(ef_, ET2_##i, a0_); \
    else if (((i) & 3) == 1) a1_ = fmaf(ef_, ET2_##i, a1_); \
    else if (((i) & 3) == 2) a2_ = fmaf(ef_, ET2_##i, a2_); \
    else                     a3_ = fmaf(ef_, ET2_##i, a3_); }

// One scan step. FS is a named ring slot (compile-time), tcur is the time index.
// Renorm: R = lane0's u2h (readfirstlane, 1 inst) -- NOT a max reduction.
// |u2h_j - u2h_0| is bounded by the per-step cross-tag spread (~2^±30 worst),
// safe in fp32. This keeps the loop-carried chain to:
//   rfl -> sub -> exp2 -> fma x8(4 chains) -> log2 -> fma.
#define SCAN_STEP(FS, tcur) { \
    const float fraw_ = FS; \
    { const int tn_ = (tcur) + 8; const int tc_ = (tn_ < L - 1) ? tn_ : (L - 1); \
      FS = frow[tc_ * NTAG + j]; } \
    const float R_ = rfl(u2h); \
    M2 += R_; \
    const float e_ = fexp2(u2h - R_); \
    const int eint_ = __float_as_int(e_); \
    REPEAT32(RL_DECL) \
    float a0_ = 0.f, a1_ = 0.f, a2_ = 0.f, a3_ = 0.f; \
    REPEAT32(FMA_T) \
    const float S_ = (a0_ + a1_) + (a2_ + a3_); \
    u2h = fmaf(fraw_, LOG2E, flog2(S_)); }

// Block = 512 threads = 8 waves. Waves 0-3: serial alpha scan, one batch each
// (lanes 0-31 = tags). Waves 4-7: gold-score gathers for the same 4 batches --
// independent co-resident waves fill the scan waves' stall cycles.
// Grid = B/4 = 256 blocks = 1 block/CU.
__global__ __launch_bounds__(512, 2) void crf_nll_kernel(
    const float* __restrict__ feats,   // B x L x 32
    const float* __restrict__ trans,   // 32 x 32
    const int*   __restrict__ tags,    // B x L
    const int*   __restrict__ wsl,     // B
    float* __restrict__ out, int B, int L)
{
    __shared__ float strans[NTAG * NTAG];
    for (int i = threadIdx.x; i < NTAG * NTAG; i += 512) strans[i] = trans[i];
    __syncthreads();

    const int wave = threadIdx.x >> 6;
    const int lane = threadIdx.x & 63;

    if (wave < 4) {
        // ================= scan waves =================
        int b = blockIdx.x * 4 + wave;
        b = __builtin_amdgcn_readfirstlane(b);
        if (lane >= 32 || b >= B) return;
        const int j = lane;

#define DECL_ET2(i) float ET2_##i = fexp2(strans[(i) * NTAG + j] * LOG2E);
        REPEAT32(DECL_ET2)
#undef DECL_ET2
        const float tS2 = strans[j * NTAG + STOP] * LOG2E;

        const int n = wsl[b];
        const float* __restrict__ frow = feats + (size_t)b * L * NTAG;

        // init (t = 0); invariant: log2-alpha_j == u2h_j + M2
        float u2h = (strans[START * NTAG + j] + frow[j]) * LOG2E;
        float M2 = 0.f;

        // prefetch ring: 8 named slots (f0 = oldest)
#define LDF(t_) frow[(((t_) < L - 1) ? (t_) : (L - 1)) * NTAG + j]
        float f0 = LDF(1), f1 = LDF(2), f2 = LDF(3), f3 = LDF(4),
              f4 = LDF(5), f5 = LDF(6), f6 = LDF(7), f7 = LDF(8);
#undef LDF

        int t = 1;
        for (; t + 8 <= n; t += 8) {
            // pin ET2 in VGPRs (zero-instruction insurance against remat/spill)
            asm volatile("" : "+v"(ET2_0),  "+v"(ET2_1),  "+v"(ET2_2),  "+v"(ET2_3),
                              "+v"(ET2_4),  "+v"(ET2_5),  "+v"(ET2_6),  "+v"(ET2_7));
            asm volatile("" : "+v"(ET2_8),  "+v"(ET2_9),  "+v"(ET2_10), "+v"(ET2_11),
                              "+v"(ET2_12), "+v"(ET2_13), "+v"(ET2_14), "+v"(ET2_15));
            asm volatile("" : "+v"(ET2_16), "+v"(ET2_17), "+v"(ET2_18), "+v"(ET2_19),
                              "+v"(ET2_20), "+v"(ET2_21), "+v"(ET2_22), "+v"(ET2_23));
            asm volatile("" : "+v"(ET2_24), "+v"(ET2_25), "+v"(ET2_26), "+v"(ET2_27),
                              "+v"(ET2_28), "+v"(ET2_29), "+v"(ET2_30), "+v"(ET2_31));
            SCAN_STEP(f0, t + 0)
            SCAN_STEP(f1, t + 1)
            SCAN_STEP(f2, t + 2)
            SCAN_STEP(f3, t + 3)
            SCAN_STEP(f4, t + 4)
            SCAN_STEP(f5, t + 5)
            SCAN_STEP(f6, t + 6)
            SCAN_STEP(f7, t + 7)
        }
        // epilogue: up to 7 remaining steps, compile-time ring slots
        if (t + 0 < n) { SCAN_STEP(f0, t + 0) }
        if (t + 1 < n) { SCAN_STEP(f1, t + 1) }
        if (t + 2 < n) { SCAN_STEP(f2, t + 2) }
        if (t + 3 < n) { SCAN_STEP(f3, t + 3) }
        if (t + 4 < n) { SCAN_STEP(f4, t + 4) }
        if (t + 5 < n) { SCAN_STEP(f5, t + 5) }
        if (t + 6 < n) { SCAN_STEP(f6, t + 6) }

        // forward score: ln2 * (M2 + Rf + log2 sum_j 2^(u2h_j - Rf + tS2_j))
        const float Rf = rfl(u2h);
        float ex = fexp2(u2h - Rf + tS2);
#pragma unroll
        for (int k = 1; k < 32; k <<= 1) ex += __shfl_xor(ex, k, 32);
        if (j == 0) atomicAdd(out, LN2 * (M2 + Rf + flog2(ex)));
    } else {
        // ================= gold waves (pure gathers, fill scan stalls) =======
        int b = blockIdx.x * 4 + (wave - 4);
        b = __builtin_amdgcn_readfirstlane(b);
        if (b >= B) return;
        const int n = wsl[b];
        const float* __restrict__ frow = feats + (size_t)b * L * NTAG;
        const int*   __restrict__ trow = tags  + (size_t)b * L;

        float acc = 0.f;
        for (int t = lane; t < L; t += 64) {
            const int tg = trow[t];
            if (t == 0) {
                // begin: trans[START, tag0] + feats[b,0,tag0]
                acc += strans[START * NTAG + tg] + frow[tg];
            } else if (t < n) {
                // middle: trans[tag_{t-1}, tag_t] + feats[b,t,tag_t]
                const int tgp = trow[t - 1];
                acc += strans[tgp * NTAG + tg] + frow[t * NTAG + tg];
            }
            if (t == n - 1) {
                // end: trans[tag_{n-1}, STOP]
                acc += strans[tg * NTAG + STOP];
            }
        }
#pragma unroll
        for (int k = 1; k < 64; k <<= 1) acc += __shfl_xor(acc, k, 64);
        if (lane == 0) atomicAdd(out, -acc);
    }
}

extern "C" void kernel_launch(void* const* d_in, const int* in_sizes, int n_in,
                              void* d_out, int out_size, void* d_ws, size_t ws_size,
                              hipStream_t stream) {
    const float* feats = (const float*)d_in[0];
    const float* trans = (const float*)d_in[1];
    const int*   tags  = (const int*)d_in[2];
    const int*   wsl   = (const int*)d_in[3];
    float* out = (float*)d_out;

    const int B = in_sizes[3];              // word_seq_lens: (B,)
    const int L = in_sizes[2] / B;          // tags: (B, L)

    (void)hipMemsetAsync(out, 0, sizeof(float), stream);
    const int grid = (B + 3) / 4;
    crf_nll_kernel<<<grid, 512, 0, stream>>>(feats, trans, tags, wsl, out, B, L);
}